// Round 1
// baseline (63856.354 us; speedup 1.0000x reference)
//
#include <hip/hip_runtime.h>

#define S         4097   // N_STATES == N_OBVS
#define SP        4100   // padded k (LDS row stride, multiple of 4 for b64 reads)
#define NBLK      256
#define NTHR      1024
#define MAXR      17     // max columns per block (block 255)
#define FS_STRIDE 4104   // fs buffer stride (16B-aligned float4 reads up to k=4099)

__device__ __forceinline__ float bf16lo(unsigned int u) { return __uint_as_float(u << 16); }
__device__ __forceinline__ float bf16hi(unsigned int u) { return __uint_as_float(u & 0xffff0000u); }

// two-level device-scope barrier: bar[0..7] group counters, bar[8] global, bar[9] generation
__device__ __forceinline__ void grid_barrier(int* bar, int target) {
  __syncthreads();
  if (threadIdx.x == 0) {
    __threadfence();  // make this block's fs stores agent-visible before arrive
    int g = (int)blockIdx.x >> 5;
    int v = __hip_atomic_fetch_add(&bar[g], 1, __ATOMIC_ACQ_REL, __HIP_MEMORY_SCOPE_AGENT);
    if ((v & 31) == 31) {
      int gv = __hip_atomic_fetch_add(&bar[8], 1, __ATOMIC_ACQ_REL, __HIP_MEMORY_SCOPE_AGENT);
      if ((gv & 7) == 7)
        __hip_atomic_store(&bar[9], target, __ATOMIC_RELEASE, __HIP_MEMORY_SCOPE_AGENT);
    }
    while (__hip_atomic_load(&bar[9], __ATOMIC_ACQUIRE, __HIP_MEMORY_SCOPE_AGENT) < target)
      __builtin_amdgcn_s_sleep(2);
    __threadfence();
  }
  __syncthreads();
}

__global__ void __launch_bounds__(NTHR) hmm_persist(
    const float* __restrict__ log_pi, const float* __restrict__ log_trans,
    const float* __restrict__ log_em, const int* __restrict__ obvs,
    float* __restrict__ bufs, int* __restrict__ bar, int T)
{
  __shared__ unsigned short plds[MAXR * SP];            // P^T tile, bf16, zero-padded
  __shared__ __align__(16) float vbuf[FS_STRIDE];       // v = exp(fs - m)
  __shared__ float red[16];

  const int tid   = threadIdx.x;
  const int lane  = tid & 63;
  const int wid   = tid >> 6;
  const int b     = blockIdx.x;
  const int jb    = b * 16;
  const int ncols = (b == NBLK - 1) ? 17 : 16;

  // ---- one-time: stage P^T tile into LDS as bf16 (consecutive lanes read consecutive j) ----
  for (int idx = tid; idx < ncols * SP; idx += NTHR) {
    int k = idx / ncols;
    int r = idx - k * ncols;
    float p = 0.f;
    if (k < S) p = __expf(log_trans[(size_t)k * S + (jb + r)]);
    unsigned int u = __float_as_uint(p);
    plds[r * SP + k] = (unsigned short)((u + 0x7fffu + ((u >> 16) & 1u)) >> 16);  // RNE bf16
  }
  if (tid < FS_STRIDE - S) vbuf[S + tid] = 0.f;          // v padding (k = 4097..4103)
  __syncthreads();

  for (int t = 0; t < T; ++t) {
    const float* fin  = (t == 0) ? log_pi : (bufs + ((t + 1) & 1) * FS_STRIDE);
    float*       fout = bufs + (t & 1) * FS_STRIDE;
    const int    obs  = obvs[t];

    // prefetch emissions for this block's columns (hides scattered-load latency)
    float em0 = 0.f, em1 = 0.f;
    if (wid < 16)               em0 = log_em[(size_t)(jb + wid) * S + obs];
    if (ncols == 17 && wid == 0) em1 = log_em[(size_t)(S - 1) * S + obs];

    // ---- phase A: load fs, global max m, v = exp(fs - m) into LDS ----
    float va[5];
    float rmax = -3.4e38f;
    #pragma unroll
    for (int i = 0; i < 5; ++i) {
      int k = tid + i * NTHR;
      va[i] = (k < S) ? fin[k] : -3.4e38f;
      rmax = fmaxf(rmax, va[i]);
    }
    #pragma unroll
    for (int off = 32; off; off >>= 1) rmax = fmaxf(rmax, __shfl_xor(rmax, off, 64));
    if (lane == 0) red[wid] = rmax;
    __syncthreads();
    float m = red[0];
    #pragma unroll
    for (int i = 1; i < 16; ++i) m = fmaxf(m, red[i]);
    #pragma unroll
    for (int i = 0; i < 5; ++i) {
      int k = tid + i * NTHR;
      if (k < S) vbuf[k] = __expf(va[i] - m);
    }
    __syncthreads();

    // ---- phase B: one column per wave, dot over all k ----
    for (int c = wid; c < ncols; c += 16) {
      const uint2*  prow = (const uint2*)(const void*)(plds + c * SP);
      const float4* v4p  = (const float4*)(const void*)vbuf;
      float acc = 0.f;
      for (int g = lane; g < 1025; g += 64) {
        float4 v4 = v4p[g];
        uint2  p  = prow[g];
        acc = fmaf(bf16lo(p.x), v4.x, acc);
        acc = fmaf(bf16hi(p.x), v4.y, acc);
        acc = fmaf(bf16lo(p.y), v4.z, acc);
        acc = fmaf(bf16hi(p.y), v4.w, acc);
      }
      #pragma unroll
      for (int off = 32; off; off >>= 1) acc += __shfl_xor(acc, off, 64);
      if (lane == 0) {
        float em = (c < 16) ? em0 : em1;
        fout[jb + c] = em + m + __logf(acc);   // acc > 0 always (argmax term >= ~1e-13)
      }
    }

    grid_barrier(bar, t + 1);
  }
}

// termination: logsumexp_j(fs[j] + log_trans[j][0])
__global__ void __launch_bounds__(1024) hmm_final(
    const float* __restrict__ fs, const float* __restrict__ log_trans,
    float* __restrict__ out)
{
  __shared__ float red[16];
  const int tid = threadIdx.x, lane = tid & 63, wid = tid >> 6;
  float va[5];
  float rmax = -3.4e38f;
  #pragma unroll
  for (int i = 0; i < 5; ++i) {
    int k = tid + i * 1024;
    va[i] = (k < S) ? (fs[k] + log_trans[(size_t)k * S]) : -3.4e38f;
    rmax = fmaxf(rmax, va[i]);
  }
  #pragma unroll
  for (int off = 32; off; off >>= 1) rmax = fmaxf(rmax, __shfl_xor(rmax, off, 64));
  if (lane == 0) red[wid] = rmax;
  __syncthreads();
  float m = red[0];
  #pragma unroll
  for (int i = 1; i < 16; ++i) m = fmaxf(m, red[i]);
  float s = 0.f;
  #pragma unroll
  for (int i = 0; i < 5; ++i) s += __expf(va[i] - m);   // pad -> exp(-huge) = 0
  #pragma unroll
  for (int off = 32; off; off >>= 1) s += __shfl_xor(s, off, 64);
  __syncthreads();
  if (lane == 0) red[wid] = s;
  __syncthreads();
  if (tid == 0) {
    float tot = 0.f;
    #pragma unroll
    for (int i = 0; i < 16; ++i) tot += red[i];
    out[0] = m + __logf(tot);
  }
}

extern "C" void kernel_launch(void* const* d_in, const int* in_sizes, int n_in,
                              void* d_out, int out_size, void* d_ws, size_t ws_size,
                              hipStream_t stream) {
  const float* log_pi    = (const float*)d_in[0];
  const float* log_trans = (const float*)d_in[1];
  const float* log_em    = (const float*)d_in[2];
  const int*   obvs      = (const int*)d_in[3];
  const int    T         = in_sizes[3];

  int*   bar  = (int*)d_ws;                       // 64 ints (256 B), reset every call
  float* bufs = (float*)((char*)d_ws + 256);      // 2 * FS_STRIDE floats

  hipMemsetAsync(bar, 0, 256, stream);
  hipLaunchKernelGGL(hmm_persist, dim3(NBLK), dim3(NTHR), 0, stream,
                     log_pi, log_trans, log_em, obvs, bufs, bar, T);
  const float* fsT = bufs + (size_t)((T - 1) & 1) * FS_STRIDE;
  hipLaunchKernelGGL(hmm_final, dim3(1), dim3(1024), 0, stream,
                     fsT, log_trans, (float*)d_out);
}

// Round 2
// 55666.260 us; speedup vs baseline: 1.1471x; 1.1471x over previous
//
#include <hip/hip_runtime.h>

#define S         4097   // N_STATES == N_OBVS
#define SP        4100   // padded k (LDS row stride, multiple of 4 for b64 reads)
#define NBLK      256
#define NTHR      1024
#define MAXR      17     // max columns per block (block 255)
#define FS_STRIDE 4104   // fs buffer stride (16B-aligned float4 reads up to k=4099)

struct Flag { int v; int pad[31]; };   // 128 B per block: no false sharing among writers

__device__ __forceinline__ float bf16lo(unsigned int u) { return __uint_as_float(u << 16); }
__device__ __forceinline__ float bf16hi(unsigned int u) { return __uint_as_float(u & 0xffff0000u); }

__global__ void __launch_bounds__(NTHR) hmm_persist(
    const float* __restrict__ log_pi, const float* __restrict__ log_trans,
    const float* __restrict__ log_em, const int* __restrict__ obvs,
    float* __restrict__ bufs, Flag* __restrict__ flags, int T)
{
  __shared__ unsigned short plds[MAXR * SP];            // P^T tile, bf16, zero-padded
  __shared__ __align__(16) float vbuf[FS_STRIDE];       // v = exp(fs - m)
  __shared__ float red[16];

  const int tid   = threadIdx.x;
  const int lane  = tid & 63;
  const int wid   = tid >> 6;
  const int b     = blockIdx.x;
  const int jb    = b * 16;
  const int ncols = (b == NBLK - 1) ? 17 : 16;

  // ---- one-time: stage P^T tile into LDS as bf16 ----
  for (int idx = tid; idx < ncols * SP; idx += NTHR) {
    int k = idx / ncols;
    int r = idx - k * ncols;
    float p = 0.f;
    if (k < S) p = __expf(log_trans[(size_t)k * S + (jb + r)]);
    unsigned int u = __float_as_uint(p);
    plds[r * SP + k] = (unsigned short)((u + 0x7fffu + ((u >> 16) & 1u)) >> 16);  // RNE bf16
  }
  if (tid < FS_STRIDE - S) vbuf[S + tid] = 0.f;          // v padding (k = 4097..4103)
  __syncthreads();

  for (int t = 0; t < T; ++t) {
    const float* fin  = (t == 0) ? log_pi : (bufs + ((t + 1) & 1) * FS_STRIDE);
    float*       fout = bufs + (t & 1) * FS_STRIDE;
    const int    obs  = obvs[t];

    // issue emission gather BEFORE the wait: scattered-HBM latency hides under spin
    float em0 = 0.f, em1 = 0.f;
    if (wid < 16)                em0 = log_em[(size_t)(jb + wid) * S + obs];
    if (ncols == 17 && wid == 0) em1 = log_em[(size_t)(S - 1) * S + obs];

    // ---- flag barrier wait: thread i spins on block i's flag (parallel, no RMW) ----
    if (t > 0 && tid < NBLK) {
      while (__hip_atomic_load(&flags[tid].v, __ATOMIC_ACQUIRE, __HIP_MEMORY_SCOPE_AGENT) < t)
        __builtin_amdgcn_s_sleep(1);
    }
    __syncthreads();

    // ---- phase A: load fs, global max m, v = exp(fs - m) into LDS ----
    float va[5];
    float rmax = -3.4e38f;
    #pragma unroll
    for (int i = 0; i < 5; ++i) {
      int k = tid + i * NTHR;
      va[i] = (k < S) ? fin[k] : -3.4e38f;
      rmax = fmaxf(rmax, va[i]);
    }
    #pragma unroll
    for (int off = 32; off; off >>= 1) rmax = fmaxf(rmax, __shfl_xor(rmax, off, 64));
    if (lane == 0) red[wid] = rmax;
    __syncthreads();
    float m = red[0];
    #pragma unroll
    for (int i = 1; i < 16; ++i) m = fmaxf(m, red[i]);
    #pragma unroll
    for (int i = 0; i < 5; ++i) {
      int k = tid + i * NTHR;
      if (k < S) vbuf[k] = __expf(va[i] - m);
    }
    __syncthreads();

    // ---- phase B: one column per wave, dot over all k ----
    for (int c = wid; c < ncols; c += 16) {
      const uint2*  prow = (const uint2*)(const void*)(plds + c * SP);
      const float4* v4p  = (const float4*)(const void*)vbuf;
      float acc = 0.f;
      for (int g = lane; g < 1025; g += 64) {
        float4 v4 = v4p[g];
        uint2  p  = prow[g];
        acc = fmaf(bf16lo(p.x), v4.x, acc);
        acc = fmaf(bf16hi(p.x), v4.y, acc);
        acc = fmaf(bf16lo(p.y), v4.z, acc);
        acc = fmaf(bf16hi(p.y), v4.w, acc);
      }
      #pragma unroll
      for (int off = 32; off; off >>= 1) acc += __shfl_xor(acc, off, 64);
      if (lane == 0) {
        float em = (c < 16) ? em0 : em1;
        fout[jb + c] = em + m + __logf(acc);
      }
    }

    // ---- flag barrier arrive: drain block's stores, flush to coherence point, release ----
    __syncthreads();                    // drains each wave's vmcnt (fout stores acked to L2)
    if (tid == 0) {
      __threadfence();                  // L2 writeback to agent coherence point
      __hip_atomic_store(&flags[b].v, t + 1, __ATOMIC_RELEASE, __HIP_MEMORY_SCOPE_AGENT);
    }
  }
}

// termination: logsumexp_j(fs[j] + log_trans[j][0])
__global__ void __launch_bounds__(1024) hmm_final(
    const float* __restrict__ fs, const float* __restrict__ log_trans,
    float* __restrict__ out)
{
  __shared__ float red[16];
  const int tid = threadIdx.x, lane = tid & 63, wid = tid >> 6;
  float va[5];
  float rmax = -3.4e38f;
  #pragma unroll
  for (int i = 0; i < 5; ++i) {
    int k = tid + i * 1024;
    va[i] = (k < S) ? (fs[k] + log_trans[(size_t)k * S]) : -3.4e38f;
    rmax = fmaxf(rmax, va[i]);
  }
  #pragma unroll
  for (int off = 32; off; off >>= 1) rmax = fmaxf(rmax, __shfl_xor(rmax, off, 64));
  if (lane == 0) red[wid] = rmax;
  __syncthreads();
  float m = red[0];
  #pragma unroll
  for (int i = 1; i < 16; ++i) m = fmaxf(m, red[i]);
  float s = 0.f;
  #pragma unroll
  for (int i = 0; i < 5; ++i) s += __expf(va[i] - m);
  #pragma unroll
  for (int off = 32; off; off >>= 1) s += __shfl_xor(s, off, 64);
  __syncthreads();
  if (lane == 0) red[wid] = s;
  __syncthreads();
  if (tid == 0) {
    float tot = 0.f;
    #pragma unroll
    for (int i = 0; i < 16; ++i) tot += red[i];
    out[0] = m + __logf(tot);
  }
}

extern "C" void kernel_launch(void* const* d_in, const int* in_sizes, int n_in,
                              void* d_out, int out_size, void* d_ws, size_t ws_size,
                              hipStream_t stream) {
  const float* log_pi    = (const float*)d_in[0];
  const float* log_trans = (const float*)d_in[1];
  const float* log_em    = (const float*)d_in[2];
  const int*   obvs      = (const int*)d_in[3];
  const int    T         = in_sizes[3];

  Flag*  flags = (Flag*)d_ws;                          // 256 * 128 B = 32 KB
  float* bufs  = (float*)((char*)d_ws + NBLK * sizeof(Flag));

  hipMemsetAsync(flags, 0, NBLK * sizeof(Flag), stream);
  hipLaunchKernelGGL(hmm_persist, dim3(NBLK), dim3(NTHR), 0, stream,
                     log_pi, log_trans, log_em, obvs, bufs, flags, T);
  const float* fsT = bufs + (size_t)((T - 1) & 1) * FS_STRIDE;
  hipLaunchKernelGGL(hmm_final, dim3(1), dim3(1024), 0, stream,
                     fsT, log_trans, (float*)d_out);
}

// Round 3
// 13683.107 us; speedup vs baseline: 4.6668x; 4.0682x over previous
//
#include <hip/hip_runtime.h>

#define S         4097   // N_STATES == N_OBVS
#define SP        4100   // padded k (LDS row stride, multiple of 4 for b64 reads)
#define NBLK      256
#define NTHR      1024
#define MAXR      17     // max columns per block (block 255)
#define FS_STRIDE 4104   // fs buffer stride (16B-aligned float4 reads up to k=4099)

__device__ __forceinline__ float bf16lo(unsigned int u) { return __uint_as_float(u << 16); }
__device__ __forceinline__ float bf16hi(unsigned int u) { return __uint_as_float(u & 0xffff0000u); }

__global__ void __launch_bounds__(NTHR) hmm_persist(
    const float* __restrict__ log_pi, const float* __restrict__ log_trans,
    const float* __restrict__ log_em, const int* __restrict__ obvs,
    int* __restrict__ bufs, int* __restrict__ flags, int T)
{
  __shared__ unsigned short plds[MAXR * SP];            // P^T tile, bf16, zero-padded
  __shared__ __align__(16) float vbuf[FS_STRIDE];       // v = exp(fs - m)
  __shared__ float red[16];

  const int tid   = threadIdx.x;
  const int lane  = tid & 63;
  const int wid   = tid >> 6;
  const int b     = blockIdx.x;
  const int jb    = b * 16;
  const int ncols = (b == NBLK - 1) ? 17 : 16;

  // ---- one-time: stage P^T tile into LDS as bf16 (plain loads, immutable input) ----
  for (int idx = tid; idx < ncols * SP; idx += NTHR) {
    int k = idx / ncols;
    int r = idx - k * ncols;
    float p = 0.f;
    if (k < S) p = __expf(log_trans[(size_t)k * S + (jb + r)]);
    unsigned int u = __float_as_uint(p);
    plds[r * SP + k] = (unsigned short)((u + 0x7fffu + ((u >> 16) & 1u)) >> 16);  // RNE bf16
  }
  if (tid < FS_STRIDE - S) vbuf[S + tid] = 0.f;          // v padding (k = 4097..4103)
  __syncthreads();

  for (int t = 0; t < T; ++t) {
    const int* fin  = (t == 0) ? (const int*)log_pi : (bufs + ((t + 1) & 1) * FS_STRIDE);
    int*       fout = bufs + (t & 1) * FS_STRIDE;
    const int  obs  = obvs[t];

    // emission gather issued BEFORE the wait: scattered load latency hides under spin.
    // Plain loads: immutable data, now stays L2-resident (no invalidates anywhere).
    float em0 = 0.f, em1 = 0.f;
    if (wid < 16)                em0 = log_em[(size_t)(jb + wid) * S + obs];
    if (ncols == 17 && wid == 0) em1 = log_em[(size_t)(S - 1) * S + obs];

    // ---- barrier wait: wave 0 polls all 256 dense flags (16 lines/round), relaxed ----
    if (t > 0 && tid < 64) {
      for (;;) {
        int f0 = __hip_atomic_load(&flags[tid      ], __ATOMIC_RELAXED, __HIP_MEMORY_SCOPE_AGENT);
        int f1 = __hip_atomic_load(&flags[tid +  64], __ATOMIC_RELAXED, __HIP_MEMORY_SCOPE_AGENT);
        int f2 = __hip_atomic_load(&flags[tid + 128], __ATOMIC_RELAXED, __HIP_MEMORY_SCOPE_AGENT);
        int f3 = __hip_atomic_load(&flags[tid + 192], __ATOMIC_RELAXED, __HIP_MEMORY_SCOPE_AGENT);
        bool ok = (f0 >= t) & (f1 >= t) & (f2 >= t) & (f3 >= t);
        if (__all(ok)) break;
        __builtin_amdgcn_s_sleep(1);
      }
    }
    __syncthreads();

    // ---- phase A: coherent fs loads (sc1, bypass stale L2), global max, v=exp(fs-m) ----
    float va[5];
    float rmax = -3.4e38f;
    #pragma unroll
    for (int i = 0; i < 5; ++i) {
      int k = tid + i * NTHR;
      va[i] = (k < S)
            ? __int_as_float(__hip_atomic_load(&fin[k], __ATOMIC_RELAXED, __HIP_MEMORY_SCOPE_AGENT))
            : -3.4e38f;
      rmax = fmaxf(rmax, va[i]);
    }
    #pragma unroll
    for (int off = 32; off; off >>= 1) rmax = fmaxf(rmax, __shfl_xor(rmax, off, 64));
    if (lane == 0) red[wid] = rmax;
    __syncthreads();
    float m = red[0];
    #pragma unroll
    for (int i = 1; i < 16; ++i) m = fmaxf(m, red[i]);
    #pragma unroll
    for (int i = 0; i < 5; ++i) {
      int k = tid + i * NTHR;
      if (k < S) vbuf[k] = __expf(va[i] - m);
    }
    __syncthreads();

    // ---- phase B: one column per wave, dot over all k (LDS-resident P, bf16) ----
    for (int c = wid; c < ncols; c += 16) {
      const uint2*  prow = (const uint2*)(const void*)(plds + c * SP);
      const float4* v4p  = (const float4*)(const void*)vbuf;
      float acc = 0.f;
      for (int g = lane; g < 1025; g += 64) {
        float4 v4 = v4p[g];
        uint2  p  = prow[g];
        acc = fmaf(bf16lo(p.x), v4.x, acc);
        acc = fmaf(bf16hi(p.x), v4.y, acc);
        acc = fmaf(bf16lo(p.y), v4.z, acc);
        acc = fmaf(bf16hi(p.y), v4.w, acc);
      }
      #pragma unroll
      for (int off = 32; off; off >>= 1) acc += __shfl_xor(acc, off, 64);
      if (lane == 0) {
        float em = (c < 16) ? em0 : em1;
        float r  = em + m + __logf(acc);
        __hip_atomic_store(&fout[jb + c], __float_as_int(r),
                           __ATOMIC_RELAXED, __HIP_MEMORY_SCOPE_AGENT);  // sc1 write-through
      }
    }

    // ---- barrier arrive: ack own coherent stores, block-sync, single relaxed flag ----
    asm volatile("s_waitcnt vmcnt(0)" ::: "memory");  // sc1 stores ack from coherence point
    __syncthreads();
    if (tid == 0)
      __hip_atomic_store(&flags[b], t + 1, __ATOMIC_RELAXED, __HIP_MEMORY_SCOPE_AGENT);
  }
}

// termination: logsumexp_j(fs[j] + log_trans[j][0])  (separate launch: caches cold-start)
__global__ void __launch_bounds__(1024) hmm_final(
    const float* __restrict__ fs, const float* __restrict__ log_trans,
    float* __restrict__ out)
{
  __shared__ float red[16];
  const int tid = threadIdx.x, lane = tid & 63, wid = tid >> 6;
  float va[5];
  float rmax = -3.4e38f;
  #pragma unroll
  for (int i = 0; i < 5; ++i) {
    int k = tid + i * 1024;
    va[i] = (k < S) ? (fs[k] + log_trans[(size_t)k * S]) : -3.4e38f;
    rmax = fmaxf(rmax, va[i]);
  }
  #pragma unroll
  for (int off = 32; off; off >>= 1) rmax = fmaxf(rmax, __shfl_xor(rmax, off, 64));
  if (lane == 0) red[wid] = rmax;
  __syncthreads();
  float m = red[0];
  #pragma unroll
  for (int i = 1; i < 16; ++i) m = fmaxf(m, red[i]);
  float s = 0.f;
  #pragma unroll
  for (int i = 0; i < 5; ++i) s += __expf(va[i] - m);
  #pragma unroll
  for (int off = 32; off; off >>= 1) s += __shfl_xor(s, off, 64);
  __syncthreads();
  if (lane == 0) red[wid] = s;
  __syncthreads();
  if (tid == 0) {
    float tot = 0.f;
    #pragma unroll
    for (int i = 0; i < 16; ++i) tot += red[i];
    out[0] = m + __logf(tot);
  }
}

extern "C" void kernel_launch(void* const* d_in, const int* in_sizes, int n_in,
                              void* d_out, int out_size, void* d_ws, size_t ws_size,
                              hipStream_t stream) {
  const float* log_pi    = (const float*)d_in[0];
  const float* log_trans = (const float*)d_in[1];
  const float* log_em    = (const float*)d_in[2];
  const int*   obvs      = (const int*)d_in[3];
  const int    T         = in_sizes[3];

  int* flags = (int*)d_ws;                        // 256 dense ints (1 KB), reset every call
  int* bufs  = (int*)((char*)d_ws + 1024);        // 2 * FS_STRIDE floats (as int bits)

  hipMemsetAsync(flags, 0, 1024, stream);
  hipLaunchKernelGGL(hmm_persist, dim3(NBLK), dim3(NTHR), 0, stream,
                     log_pi, log_trans, log_em, obvs, bufs, flags, T);
  const float* fsT = (const float*)(bufs + (size_t)((T - 1) & 1) * FS_STRIDE);
  hipLaunchKernelGGL(hmm_final, dim3(1), dim3(1024), 0, stream,
                     fsT, log_trans, (float*)d_out);
}

// Round 4
// 8551.768 us; speedup vs baseline: 7.4670x; 1.6000x over previous
//
#include <hip/hip_runtime.h>

#define S         4097   // N_STATES == N_OBVS
#define SP        4100   // padded k (LDS row stride, multiple of 4 for b64 reads)
#define NBLK      256
#define NTHR      1024
#define MAXR      17     // max columns per block (block 255)
#define FS_STRIDE 4104   // vbuf stride (16B-aligned float4 reads up to k=4099)
#define PAIRS     4097   // (val,tag) int2 pairs per fs buffer

typedef int   i32x4 __attribute__((ext_vector_type(4)));
typedef int   i32x2 __attribute__((ext_vector_type(2)));

__device__ __forceinline__ float bf16lo(unsigned int u) { return __uint_as_float(u << 16); }
__device__ __forceinline__ float bf16hi(unsigned int u) { return __uint_as_float(u & 0xffff0000u); }

__global__ void __launch_bounds__(NTHR) hmm_persist(
    const float* __restrict__ log_pi, const float* __restrict__ log_trans,
    const float* __restrict__ log_em, const int* __restrict__ obvs,
    i32x2* __restrict__ pairs, int T)
{
  __shared__ unsigned short plds[MAXR * SP];            // P^T tile, bf16, zero-padded
  __shared__ __align__(16) float vbuf[FS_STRIDE];       // v = exp(fs - m)
  __shared__ float red[16];                             // per-wave maxima
  __shared__ float red2[MAXR];                          // per-column results

  const int tid   = threadIdx.x;
  const int lane  = tid & 63;
  const int wid   = tid >> 6;
  const int b     = blockIdx.x;
  const int jb    = b * 16;
  const int ncols = (b == NBLK - 1) ? 17 : 16;

  // ---- one-time: stage P^T tile into LDS as bf16 ----
  for (int idx = tid; idx < ncols * SP; idx += NTHR) {
    int k = idx / ncols;
    int r = idx - k * ncols;
    float p = 0.f;
    if (k < S) p = __expf(log_trans[(size_t)k * S + (jb + r)]);
    unsigned int u = __float_as_uint(p);
    plds[r * SP + k] = (unsigned short)((u + 0x7fffu + ((u >> 16) & 1u)) >> 16);  // RNE bf16
  }
  if (tid < FS_STRIDE - S) vbuf[S + tid] = 0.f;          // v padding (k = 4097..4103)
  __syncthreads();

  for (int t = 0; t < T; ++t) {
    const i32x2* pin  = pairs + ((t + 1) & 1) * PAIRS;   // W_{t-1}, tags == t when ready
    i32x2*       pout = pairs + (t & 1) * PAIRS;
    const int    obs  = obvs[t];

    // emission gather first: scattered L2/L3 latency hides under the data-poll
    float em0 = 0.f, em1 = 0.f;
    if (wid < 16)                em0 = log_em[(size_t)(jb + wid) * S + obs];
    if (ncols == 17 && wid == 0) em1 = log_em[(size_t)(S - 1) * S + obs];

    // ---- phase A: fused barrier+broadcast — poll (val,tag) pairs until fresh ----
    float va0, va1, va2, va3, vat = -3.4e38f;
    if (t == 0) {
      const float4 v4 = *(const float4*)(log_pi + 4 * tid);
      va0 = v4.x; va1 = v4.y; va2 = v4.z; va3 = v4.w;
      if (tid == 0) vat = log_pi[4096];
    } else {
      const i32x2* pa = pin + 4 * tid;
      const i32x2* pb = pa + 2;
      const i32x2* pt = pin + 4096;
      i32x4 A, B; i32x2 Tl;
      for (;;) {
        asm volatile("global_load_dwordx4 %0, %2, off sc0 sc1\n\t"
                     "global_load_dwordx4 %1, %3, off sc0 sc1"
                     : "=&v"(A), "=&v"(B) : "v"(pa), "v"(pb) : "memory");
        if (tid == 0)
          asm volatile("global_load_dwordx2 %0, %1, off sc0 sc1"
                       : "=&v"(Tl) : "v"(pt) : "memory");
        asm volatile("s_waitcnt vmcnt(0)" ::: "memory");
        __builtin_amdgcn_sched_barrier(0);
        bool ok = (A.y >= t) & (A.w >= t) & (B.y >= t) & (B.w >= t);
        if (tid == 0) ok &= (Tl.y >= t);
        if (ok) {
          va0 = __int_as_float(A.x); va1 = __int_as_float(A.z);
          va2 = __int_as_float(B.x); va3 = __int_as_float(B.z);
          if (tid == 0) vat = __int_as_float(Tl.x);
          break;
        }
        __builtin_amdgcn_s_sleep(8);
      }
    }

    // global max over the 4097 values this block just loaded
    float rmax = fmaxf(fmaxf(va0, va1), fmaxf(va2, va3));
    rmax = fmaxf(rmax, vat);
    #pragma unroll
    for (int off = 32; off; off >>= 1) rmax = fmaxf(rmax, __shfl_xor(rmax, off, 64));
    if (lane == 0) red[wid] = rmax;
    __syncthreads();
    float m = red[0];
    #pragma unroll
    for (int i = 1; i < 16; ++i) m = fmaxf(m, red[i]);

    float4 ve;
    ve.x = __expf(va0 - m); ve.y = __expf(va1 - m);
    ve.z = __expf(va2 - m); ve.w = __expf(va3 - m);
    *(float4*)(vbuf + 4 * tid) = ve;
    if (tid == 0) vbuf[4096] = __expf(vat - m);
    __syncthreads();

    // ---- phase B: one column per wave, dot over all k (LDS-resident bf16 P) ----
    for (int c = wid; c < ncols; c += 16) {
      const uint2*  prow = (const uint2*)(const void*)(plds + c * SP);
      const float4* v4p  = (const float4*)(const void*)vbuf;
      float acc = 0.f;
      for (int g = lane; g < 1025; g += 64) {
        float4 v4 = v4p[g];
        uint2  p  = prow[g];
        acc = fmaf(bf16lo(p.x), v4.x, acc);
        acc = fmaf(bf16hi(p.x), v4.y, acc);
        acc = fmaf(bf16lo(p.y), v4.z, acc);
        acc = fmaf(bf16hi(p.y), v4.w, acc);
      }
      #pragma unroll
      for (int off = 32; off; off >>= 1) acc += __shfl_xor(acc, off, 64);
      if (lane == 0) {
        float em = (c < 16) ? em0 : em1;
        red2[c] = em + m + __logf(acc);
      }
    }
    __syncthreads();

    // ---- publish: one wave stores (val, t+1) pairs — no drain, no flag ----
    if (wid == 0 && lane < ncols) {
      i32x2 vt;
      vt.x = __float_as_int(red2[lane]);
      vt.y = t + 1;
      const i32x2* dst = pout + jb + lane;
      asm volatile("global_store_dwordx2 %0, %1, off sc0 sc1"
                   :: "v"(dst), "v"(vt) : "memory");
    }
    // safe to loop: red/red2/vbuf reuse is ordered by the syncthreads above and
    // the next iteration's syncthreads before any rewrite.
  }
}

// termination: logsumexp_j(fs[j] + log_trans[j][0])
__global__ void __launch_bounds__(1024) hmm_final(
    const i32x2* __restrict__ fsp, const float* __restrict__ log_trans,
    float* __restrict__ out)
{
  __shared__ float red[16];
  const int tid = threadIdx.x, lane = tid & 63, wid = tid >> 6;
  float va[5];
  float rmax = -3.4e38f;
  #pragma unroll
  for (int i = 0; i < 5; ++i) {
    int k = tid + i * 1024;
    va[i] = (k < S) ? (__int_as_float(fsp[k].x) + log_trans[(size_t)k * S]) : -3.4e38f;
    rmax = fmaxf(rmax, va[i]);
  }
  #pragma unroll
  for (int off = 32; off; off >>= 1) rmax = fmaxf(rmax, __shfl_xor(rmax, off, 64));
  if (lane == 0) red[wid] = rmax;
  __syncthreads();
  float m = red[0];
  #pragma unroll
  for (int i = 1; i < 16; ++i) m = fmaxf(m, red[i]);
  float s = 0.f;
  #pragma unroll
  for (int i = 0; i < 5; ++i) s += __expf(va[i] - m);
  #pragma unroll
  for (int off = 32; off; off >>= 1) s += __shfl_xor(s, off, 64);
  __syncthreads();
  if (lane == 0) red[wid] = s;
  __syncthreads();
  if (tid == 0) {
    float tot = 0.f;
    #pragma unroll
    for (int i = 0; i < 16; ++i) tot += red[i];
    out[0] = m + __logf(tot);
  }
}

extern "C" void kernel_launch(void* const* d_in, const int* in_sizes, int n_in,
                              void* d_out, int out_size, void* d_ws, size_t ws_size,
                              hipStream_t stream) {
  const float* log_pi    = (const float*)d_in[0];
  const float* log_trans = (const float*)d_in[1];
  const float* log_em    = (const float*)d_in[2];
  const int*   obvs      = (const int*)d_in[3];
  const int    T         = in_sizes[3];

  i32x2* pairs = (i32x2*)d_ws;                       // 2 * 4097 * 8 B = 65,552 B
  hipMemsetAsync(pairs, 0, 2 * PAIRS * sizeof(i32x2), stream);  // tags < 1: replay-safe

  hipLaunchKernelGGL(hmm_persist, dim3(NBLK), dim3(NTHR), 0, stream,
                     log_pi, log_trans, log_em, obvs, pairs, T);
  const i32x2* fsT = pairs + (size_t)((T - 1) & 1) * PAIRS;
  hipLaunchKernelGGL(hmm_final, dim3(1), dim3(1024), 0, stream,
                     fsT, log_trans, (float*)d_out);
}

// Round 7
// 8364.835 us; speedup vs baseline: 7.6339x; 1.0223x over previous
//
#include <hip/hip_runtime.h>

#define S      4097              // states
#define KP     4128              // padded K (multiple of 32 for MFMA)
#define NBLK   256
#define NTHR   1024
#define PAIRS  4097              // (val,tag) i32x2 pairs per fs buffer

typedef int   i32x4  __attribute__((ext_vector_type(4)));
typedef int   i32x2v __attribute__((ext_vector_type(2)));
typedef float f32x4  __attribute__((ext_vector_type(4)));
typedef short bf16x8 __attribute__((ext_vector_type(8)));

__device__ __forceinline__ float blo(unsigned int u) { return __uint_as_float(u << 16); }
__device__ __forceinline__ float bhi(unsigned int u) { return __uint_as_float(u & 0xffff0000u); }
__device__ __forceinline__ unsigned short rne_bf16(float x) {
  unsigned u = __float_as_uint(x);
  return (unsigned short)((u + 0x7fffu + ((u >> 16) & 1u)) >> 16);
}

__global__ void __launch_bounds__(NTHR) hmm_persist(
    const float* __restrict__ log_pi, const float* __restrict__ log_trans,
    const float* __restrict__ log_em, const int* __restrict__ obvs,
    i32x2v* __restrict__ pairs, int T)
{
  __shared__ __align__(16) unsigned short plds[17 * KP];  // P^T bf16, 140,352 B
  __shared__ __align__(16) unsigned short vb[KP];         // v bf16
  __shared__ __align__(16) float part[8][256];            // MFMA partials
  __shared__ float red[16];
  __shared__ float em_lds[17];
  __shared__ float part2[8];

  const int tid = threadIdx.x, lane = tid & 63, wid = tid >> 6;
  const int b = blockIdx.x, jb = b * 16;
  const int ncols = (b == NBLK - 1) ? 17 : 16;

  // ---- one-time: stage P^T tile as bf16, zero-padded to KP ----
  for (int idx = tid; idx < ncols * KP; idx += NTHR) {
    int k = idx / ncols, r = idx - k * ncols;
    float p = (k < S) ? __expf(log_trans[(size_t)k * S + (jb + r)]) : 0.f;
    plds[r * KP + k] = rne_bf16(p);
  }
  if (tid < 31) vb[4097 + tid] = 0;                       // static v padding
  __syncthreads();

  for (int t = 0; t < T; ++t) {
    const i32x2v* pin  = pairs + ((t + 1) & 1) * PAIRS;   // tags == t when fresh
    i32x2v*       pout = pairs + (t & 1) * PAIRS;
    const int     obs  = obvs[t];

    // wave 15: issue em gather early (latency hides under poll)
    float emv = 0.f;
    if (wid == 15 && lane < ncols) emv = log_em[(size_t)(jb + lane) * S + obs];

    // ---- phase A: fused barrier+broadcast — R4-proven fp32 (val,tag) poll ----
    float va0, va1, va2, va3, va4 = -3.4e38f;
    if (t == 0) {
      const float4 v4 = *(const float4*)(log_pi + 4 * tid);
      va0 = v4.x; va1 = v4.y; va2 = v4.z; va3 = v4.w;
      if (tid == 0) va4 = log_pi[4096];
    } else {
      const i32x2v* pa = pin + 4 * tid;
      const i32x2v* pb = pa + 2;
      const i32x2v* pt = pin + 4096;
      i32x4 A, B; i32x2v Tl;
      for (;;) {
        asm volatile("global_load_dwordx4 %0, %2, off sc0 sc1\n\t"
                     "global_load_dwordx4 %1, %3, off sc0 sc1"
                     : "=&v"(A), "=&v"(B) : "v"(pa), "v"(pb) : "memory");
        if (tid == 0)
          asm volatile("global_load_dwordx2 %0, %1, off sc0 sc1"
                       : "=&v"(Tl) : "v"(pt) : "memory");
        asm volatile("s_waitcnt vmcnt(0)" ::: "memory");
        __builtin_amdgcn_sched_barrier(0);
        bool ok = (A.y >= t) & (A.w >= t) & (B.y >= t) & (B.w >= t);
        if (tid == 0) ok &= (Tl.y >= t);
        if (ok) {
          va0 = __int_as_float(A.x); va1 = __int_as_float(A.z);
          va2 = __int_as_float(B.x); va3 = __int_as_float(B.z);
          if (tid == 0) va4 = __int_as_float(Tl.x);
          break;
        }
        __builtin_amdgcn_s_sleep(8);
      }
    }

    // block-wide max (red[lane&15] + shfl tree)
    float rmx = fmaxf(fmaxf(va0, va1), fmaxf(fmaxf(va2, va3), va4));
    #pragma unroll
    for (int off = 32; off; off >>= 1) rmx = fmaxf(rmx, __shfl_xor(rmx, off, 64));
    if (lane == 0) red[wid] = rmx;
    __syncthreads();
    float m = red[lane & 15];
    #pragma unroll
    for (int off = 8; off; off >>= 1) m = fmaxf(m, __shfl_xor(m, off, 64));

    // v = exp(va - m) -> bf16 (software RNE)
    float v0 = __expf(va0 - m), v1 = __expf(va1 - m);
    float v2 = __expf(va2 - m), v3 = __expf(va3 - m);
    unsigned b0 = rne_bf16(v0), b1 = rne_bf16(v1);
    unsigned b2 = rne_bf16(v2), b3 = rne_bf16(v3);
    *(int2*)(vb + 4 * tid) = make_int2((int)((b1 << 16) | b0), (int)((b3 << 16) | b2));
    if (tid == 0)
      *(int*)(vb + 4096) = (int)rne_bf16(__expf(va4 - m));  // [4096]=v4, [4097]=0
    if (wid == 15 && lane < ncols) em_lds[lane] = emv;
    __syncthreads();

    // ---- phase B: MFMA. A = P^T rows (j = lane&15, 8 contig k), B = v broadcast ----
    if (wid < 8) {
      const int kb0 = wid * 16, kbn = (wid == 7) ? 17 : 16;   // 129 K-blocks of 32
      const uint4* ap = ((const uint4*)plds) + (lane & 15) * (KP / 8);
      const uint4* vp = (const uint4*)vb;
      const int g = lane >> 4;
      f32x4 accA = {0.f, 0.f, 0.f, 0.f}, accB = {0.f, 0.f, 0.f, 0.f};
      for (int mm = kb0; mm + 1 < kb0 + kbn; mm += 2) {
        bf16x8 a0 = __builtin_bit_cast(bf16x8, ap[mm * 4 + g]);
        bf16x8 w0 = __builtin_bit_cast(bf16x8, vp[mm * 4 + g]);
        accA = __builtin_amdgcn_mfma_f32_16x16x32_bf16(a0, w0, accA, 0, 0, 0);
        bf16x8 a1 = __builtin_bit_cast(bf16x8, ap[(mm + 1) * 4 + g]);
        bf16x8 w1 = __builtin_bit_cast(bf16x8, vp[(mm + 1) * 4 + g]);
        accB = __builtin_amdgcn_mfma_f32_16x16x32_bf16(a1, w1, accB, 0, 0, 0);
      }
      if (kbn & 1) {
        int mm = kb0 + kbn - 1;
        bf16x8 a0 = __builtin_bit_cast(bf16x8, ap[mm * 4 + g]);
        bf16x8 w0 = __builtin_bit_cast(bf16x8, vp[mm * 4 + g]);
        accA = __builtin_amdgcn_mfma_f32_16x16x32_bf16(a0, w0, accA, 0, 0, 0);
      }
      accA += accB;
      *(f32x4*)&part[wid][lane * 4] = accA;
    } else if (b == NBLK - 1) {
      // waves 8-15: column 16 (state 4096) VALU dot, split 8 ways
      float a16 = 0.f;
      const uint4* prow = (const uint4*)(plds + 16 * KP);
      const uint4* vp   = (const uint4*)vb;
      for (int ot = (wid - 8) * 64 + lane; ot < KP / 8; ot += 512) {
        uint4 pw = prow[ot], vw = vp[ot];
        a16 += blo(pw.x) * blo(vw.x) + bhi(pw.x) * bhi(vw.x);
        a16 += blo(pw.y) * blo(vw.y) + bhi(pw.y) * bhi(vw.y);
        a16 += blo(pw.z) * blo(vw.z) + bhi(pw.z) * bhi(vw.z);
        a16 += blo(pw.w) * blo(vw.w) + bhi(pw.w) * bhi(vw.w);
      }
      #pragma unroll
      for (int off = 32; off; off >>= 1) a16 += __shfl_xor(a16, off, 64);
      if (lane == 0) part2[wid - 8] = a16;
    }
    __syncthreads();

    // ---- finalize + publish (wave 15): fs_new = em + m + log(dot)  [the R6 bug: m] ----
    const int tag = t + 1;
    if (wid == 15) {
      f32x4 tot = {0.f, 0.f, 0.f, 0.f};
      #pragma unroll
      for (int p = 0; p < 8; ++p) tot += *(const f32x4*)&part[p][lane * 4];
      if ((lane & 15) == 0) {                  // lanes 0,16,32,48: rows 4g..4g+3 (col 0)
        const int j0 = (lane >> 4) * 4;
        float r0 = em_lds[j0 + 0] + m + __logf(tot.x);
        float r1 = em_lds[j0 + 1] + m + __logf(tot.y);
        float r2 = em_lds[j0 + 2] + m + __logf(tot.z);
        float r3 = em_lds[j0 + 3] + m + __logf(tot.w);
        i32x4 o1, o2;
        o1.x = __float_as_int(r0); o1.y = tag; o1.z = __float_as_int(r1); o1.w = tag;
        o2.x = __float_as_int(r2); o2.y = tag; o2.z = __float_as_int(r3); o2.w = tag;
        const i32x2v* d1 = pout + jb + j0;
        const i32x2v* d2 = pout + jb + j0 + 2;
        asm volatile("global_store_dwordx4 %0, %1, off sc0 sc1"
                     :: "v"(d1), "v"(o1) : "memory");
        asm volatile("global_store_dwordx4 %0, %1, off sc0 sc1"
                     :: "v"(d2), "v"(o2) : "memory");
      }
      if (b == NBLK - 1 && lane == 0) {
        float s16 = 0.f;
        #pragma unroll
        for (int p = 0; p < 8; ++p) s16 += part2[p];
        float r16 = em_lds[16] + m + __logf(s16);
        i32x2v o; o.x = __float_as_int(r16); o.y = tag;
        const i32x2v* dst = pout + 4096;
        asm volatile("global_store_dwordx2 %0, %1, off sc0 sc1"
                     :: "v"(dst), "v"(o) : "memory");
      }
    }
    __syncthreads();
  }
}

// termination: logsumexp_j(fs[j] + log_trans[j][0])
__global__ void __launch_bounds__(1024) hmm_final(
    const i32x2v* __restrict__ fsp, const float* __restrict__ log_trans,
    float* __restrict__ out)
{
  __shared__ float red[16];
  const int tid = threadIdx.x, lane = tid & 63, wid = tid >> 6;
  float va[5];
  float rmax = -3.4e38f;
  #pragma unroll
  for (int i = 0; i < 5; ++i) {
    int k = tid + i * 1024;
    va[i] = (k < S) ? (__int_as_float(fsp[k].x) + log_trans[(size_t)k * S]) : -3.4e38f;
    rmax = fmaxf(rmax, va[i]);
  }
  #pragma unroll
  for (int off = 32; off; off >>= 1) rmax = fmaxf(rmax, __shfl_xor(rmax, off, 64));
  if (lane == 0) red[wid] = rmax;
  __syncthreads();
  float m = red[0];
  #pragma unroll
  for (int i = 1; i < 16; ++i) m = fmaxf(m, red[i]);
  float s = 0.f;
  #pragma unroll
  for (int i = 0; i < 5; ++i) s += __expf(va[i] - m);
  #pragma unroll
  for (int off = 32; off; off >>= 1) s += __shfl_xor(s, off, 64);
  __syncthreads();
  if (lane == 0) red[wid] = s;
  __syncthreads();
  if (tid == 0) {
    float tot = 0.f;
    #pragma unroll
    for (int i = 0; i < 16; ++i) tot += red[i];
    out[0] = m + __logf(tot);
  }
}

extern "C" void kernel_launch(void* const* d_in, const int* in_sizes, int n_in,
                              void* d_out, int out_size, void* d_ws, size_t ws_size,
                              hipStream_t stream) {
  const float* log_pi    = (const float*)d_in[0];
  const float* log_trans = (const float*)d_in[1];
  const float* log_em    = (const float*)d_in[2];
  const int*   obvs      = (const int*)d_in[3];
  const int    T         = in_sizes[3];

  i32x2v* pairs = (i32x2v*)d_ws;                     // 2 * 4097 * 8 B
  hipMemsetAsync(pairs, 0, 2 * PAIRS * sizeof(i32x2v), stream);  // tags < 1: replay-safe

  hipLaunchKernelGGL(hmm_persist, dim3(NBLK), dim3(NTHR), 0, stream,
                     log_pi, log_trans, log_em, obvs, pairs, T);
  const i32x2v* fsT = pairs + (size_t)((T - 1) & 1) * PAIRS;
  hipLaunchKernelGGL(hmm_final, dim3(1), dim3(1024), 0, stream,
                     fsT, log_trans, (float*)d_out);
}